// Round 1
// baseline (346.334 us; speedup 1.0000x reference)
//
#include <hip/hip_runtime.h>

// CharAttention: per (b,w) causal char-attention; only row x_end_idx[b,w]
// survives the final gather -> compute only that row, and FOLD the weights:
//   M_h = 0.25 * Wq_h @ Wk_h^T  (32x32/head)  ->  rk_h[c] = xq . Mt_h[c][:]
//   P_h[e][c] = sum_d Wv[e][16h+d] Wproj[16h+d][c] -> out[c] = sum_h y_h . Pt_h[c][:]
// This removes the q/o/proj phases, all 16 dynamic shuffles, one fence, and
// two global weight-latency phases from the per-wave critical path.
// M,P are launch constants: computed once by a tiny pre-kernel into __device__
// globals (8 KB each, L1-resident for the main kernel).
//
// Main kernel phases (4 lgkmcnt fences, all wave-local, no __syncthreads):
//   stage x rows (zero-fill past L so the y phase is a static 24-unroll)
//   rk  : lane(c=i32,h=half): rks[h][c] = xq . Mt[h][c][:]
//   s/sm: lane(j=i32,h=half): softmax(xs[j] . rks[h]), masked j>qidx -> 0
//   y   : lane(c=i32,h=half): ys[h][c] = sum_j p[h][j] xs[j][c] (static unroll)
//   out : lane(c=i32,h=half): sum_e ys[h][e] Pt[h][c][e], xor-32 combine, +resid
// One wave per problem, 4 waves/block, grid 16384, ~15.8 KB LDS -> 32 waves/CU.

#define CB      24
#define CC      32
#define DD      16
#define THREEC  96
#define NBW     (512 * 128)
#define WPB     4
#define XSS     34              // xs row stride: even (float2-aligned), <=2-way banks

__device__ __align__(16) float g_Mt[2][CC][CC];  // [h][c][e]
__device__ __align__(16) float g_Pt[2][CC][CC];  // [h][c][e]

__global__ void precompute_mp(const float* __restrict__ w_attn,
                              const float* __restrict__ w_proj)
{
    const int idx = blockIdx.x * 256 + threadIdx.x;   // 2048 entries
    const int h = idx >> 10, c = (idx >> 5) & 31, e = idx & 31;
    float m = 0.f, p = 0.f;
    #pragma unroll
    for (int d = 0; d < DD; ++d) {
        const int i = DD * h + d;
        m = fmaf(w_attn[e * THREEC + i],          w_attn[c * THREEC + CC + i], m);
        p = fmaf(w_attn[e * THREEC + 2 * CC + i], w_proj[i * CC + c],          p);
    }
    g_Mt[h][c][e] = 0.25f * m;                    // fold 1/sqrt(D)
    g_Pt[h][c][e] = p;
}

struct __align__(16) WaveSmem {
    float xs[CB][XSS];          // staged x rows (3264 B)
    float rks[2][CC];           // rk per head, scale folded (256 B)
    float ps[2][CC];            // softmax probs; masked slots 0 (256 B)
    float ys[2][CC];            // p @ x per head (256 B)
};                              // 4032 B -> 4 waves = 15.75 KB/block

__device__ __forceinline__ void wave_fence() {
    __asm__ volatile("s_waitcnt lgkmcnt(0)" ::: "memory");
}

__global__ __launch_bounds__(256, 8) void char_attn_kernel(
    const float* __restrict__ x,        // [B*W, 24, 32]
    const int*   __restrict__ xend,     // [B*W]
    float*       __restrict__ out)      // [B*W, 32]
{
    __shared__ WaveSmem sm[WPB];

    const int tid  = threadIdx.x;
    const int lane = tid & 63;
    const int wave = tid >> 6;
    WaveSmem& S = sm[wave];

    const int bid  = blockIdx.x * WPB + wave;   // one problem per wave
    const int i32  = lane & 31;
    const int half = lane >> 5;

    const int qidx = xend[bid];                 // wave-uniform
    const int L    = qidx + 1;
    const float* xb = x + (size_t)bid * (CB * CC);

    // ---- stage x rows; rows >= L zero-filled (enables static y unroll) ----
    {
        const float2* xb2 = (const float2*)xb;
        const int n2 = L * (CC / 2);
        #pragma unroll
        for (int t0 = 0; t0 < CB * (CC / 2); t0 += 64) {
            const int t = t0 + lane;
            float2 v = make_float2(0.f, 0.f);
            if (t < n2) v = xb2[t];             // predicated load, coalesced
            const int r = t >> 4, c = (t & 15) * 2;
            *(float2*)&S.xs[r][c] = v;          // 8B-aligned (XSS even)
        }
    }
    wave_fence();                               // xs visible in-wave

    // ---- rk: lane=(c=i32, h=half): rks[h][c] = xq . Mt[h][c][:] ----
    {
        const float4* m4 = (const float4*)&g_Mt[half][i32][0];
        float a0 = 0.f, a1 = 0.f, a2 = 0.f, a3 = 0.f;
        #pragma unroll
        for (int e4 = 0; e4 < 8; ++e4) {
            const float4 mv = m4[e4];                               // L1-hot 16B
            const float2 x0 = *(const float2*)&S.xs[qidx][e4 * 4];      // broadcast
            const float2 x1 = *(const float2*)&S.xs[qidx][e4 * 4 + 2];  // broadcast
            a0 = fmaf(mv.x, x0.x, a0);
            a1 = fmaf(mv.y, x0.y, a1);
            a2 = fmaf(mv.z, x1.x, a2);
            a3 = fmaf(mv.w, x1.y, a3);
        }
        S.rks[half][i32] = (a0 + a1) + (a2 + a3);
    }
    wave_fence();                               // rks visible

    // ---- scores + softmax: lane=(h=half, j=i32) ----
    {
        float sc = -INFINITY;
        if (i32 <= qidx) {
            float a0 = 0.f, a1 = 0.f;
            #pragma unroll
            for (int c = 0; c < CC; c += 2) {
                const float2 xv = *(const float2*)&S.xs[i32][c];     // 2-way banks: free
                const float2 rv = *(const float2*)&S.rks[half][c];   // broadcast
                a0 = fmaf(xv.x, rv.x, a0);
                a1 = fmaf(xv.y, rv.y, a1);
            }
            sc = a0 + a1;
        }
        float m = sc;
        #pragma unroll
        for (int off = 16; off >= 1; off >>= 1)
            m = fmaxf(m, __shfl_xor(m, off));
        const float e = (i32 <= qidx) ? __expf(sc - m) : 0.f;
        float sum = e;
        #pragma unroll
        for (int off = 16; off >= 1; off >>= 1)
            sum += __shfl_xor(sum, off);
        S.ps[half][i32] = __fdividef(e, sum);   // 0 for masked j
    }
    wave_fence();                               // ps visible

    // ---- y: static 24-unroll; ps[j]=0 and xs[j]=0 past L keep it exact ----
    {
        float a0 = 0.f, a1 = 0.f;
        #pragma unroll
        for (int j = 0; j < CB; j += 2) {
            const float2 p2 = *(const float2*)&S.ps[half][j];        // broadcast
            a0 = fmaf(p2.x, S.xs[j][i32],     a0);                   // conflict-free
            a1 = fmaf(p2.y, S.xs[j + 1][i32], a1);
        }
        S.ys[half][i32] = a0 + a1;
    }
    wave_fence();                               // ys visible

    // ---- out[c] = sum_h ys[h] . Pt[h][c][:] + residual ----
    {
        const float4* p4 = (const float4*)&g_Pt[half][i32][0];
        float a0 = 0.f, a1 = 0.f, a2 = 0.f, a3 = 0.f;
        #pragma unroll
        for (int e4 = 0; e4 < 8; ++e4) {
            const float4 pv = p4[e4];                               // L1-hot 16B
            const float2 y0 = *(const float2*)&S.ys[half][e4 * 4];      // broadcast
            const float2 y1 = *(const float2*)&S.ys[half][e4 * 4 + 2];  // broadcast
            a0 = fmaf(pv.x, y0.x, a0);
            a1 = fmaf(pv.y, y0.y, a1);
            a2 = fmaf(pv.z, y1.x, a2);
            a3 = fmaf(pv.w, y1.y, a3);
        }
        float t = (a0 + a1) + (a2 + a3);
        t += __shfl_xor(t, 32);                 // combine the two heads
        if (lane < CC)
            out[(size_t)bid * CC + i32] = t + S.xs[qidx][i32];
    }
}

extern "C" void kernel_launch(void* const* d_in, const int* in_sizes, int n_in,
                              void* d_out, int out_size, void* d_ws, size_t ws_size,
                              hipStream_t stream) {
    const float* x      = (const float*)d_in[0];
    const int*   xend   = (const int*)d_in[1];
    const float* w_attn = (const float*)d_in[2];
    const float* w_proj = (const float*)d_in[3];
    float* out = (float*)d_out;

    precompute_mp<<<dim3(8), dim3(256), 0, stream>>>(w_attn, w_proj);
    char_attn_kernel<<<dim3(NBW / WPB), dim3(WPB * 64), 0, stream>>>(
        x, xend, out);
}